// Round 10
// baseline (381.069 us; speedup 1.0000x reference)
//
#include <hip/hip_runtime.h>
#include <hip/hip_cooperative_groups.h>
#include <math.h>

namespace cg = cooperative_groups;

#define BS 32
#define NM 64
#define NA 8400
#define NC 80
#define TOPKK 13
#define N_TOT (BS * NA)
#define TPL 8  // per-lane candidate bound: ceil(1156/256)+ceil(324/256)+1 = 8

// CIoU (box1 = gt, box2 = pred) with gt-side terms hoisted; clipped at 0.
// Bit-identical to reference _ciou (eps=1e-7) + jnp.clip(x,0) (validated R2-R9).
__device__ __forceinline__ float ciou_clip_pre(
    float gx1, float gy1, float gx2, float gy2,
    float area1, float at1,
    float px1, float py1, float px2, float py2) {
    const float eps = 1e-7f;
    float w2 = px2 - px1, h2 = py2 - py1 + eps;
    float iw = fmaxf(fminf(gx2, px2) - fmaxf(gx1, px1), 0.f);
    float ih = fmaxf(fminf(gy2, py2) - fmaxf(gy1, py1), 0.f);
    float inter = iw * ih;
    float uni = area1 + w2 * h2 - inter + eps;
    float iou = inter / uni;
    float cw = fmaxf(gx2, px2) - fminf(gx1, px1);
    float ch = fmaxf(gy2, py2) - fminf(gy1, py1);
    float c2 = cw * cw + ch * ch + eps;
    float dx = px1 + px2 - gx1 - gx2;
    float dy = py1 + py2 - gy1 - gy2;
    float rho2 = (dx * dx + dy * dy) * 0.25f;
    float dat = atanf(w2 / h2) - at1;
    float v = 0.4052847345693511f * dat * dat;  // 4/pi^2
    float al = v / (v - iou + 1.0000001f);      // 1.0 + eps
    return fmaxf(iou - (rho2 / c2 + v * al), 0.f);
}

__device__ __forceinline__ unsigned long long umax64(unsigned long long a,
                                                     unsigned long long b) {
    return a > b ? a : b;
}

// anchor index -> (ax, ay) exactly: (i+0.5)*stride, bit-identical to reference.
__device__ __forceinline__ void anchor_xy(int a, float& ax, float& ay) {
    int loc, n; float s;
    if (a < 6400)      { loc = a;        n = 80; s = 8.f;  }
    else if (a < 8000) { loc = a - 6400; n = 40; s = 16.f; }
    else               { loc = a - 8000; n = 20; s = 32.f; }
    int row = loc / n, col = loc - row * n;
    ax = ((float)col + 0.5f) * s;
    ay = ((float)row + 0.5f) * s;
}

// ============================== MEGA KERNEL =================================
// All four R6 phases fused with cooperative grid syncs. 1024 blocks x 256,
// __launch_bounds__(256,4) caps VGPR<=128 -> 4 blocks/CU -> full co-residency
// on 256 CUs. Phase bodies are verbatim R6; barriers kept wave-uniform via
// uniform iteration counts + guarded work (never guarded barriers).
__global__ __launch_bounds__(256, 4) void k_mega(
    const float* __restrict__ pd_scores,
    const float* __restrict__ pd_bboxes,
    const int* __restrict__ gt_labels,
    const float* __restrict__ gt_bboxes,
    const float* __restrict__ mask_gt,
    int* __restrict__ fg,
    int* __restrict__ assignm,
    float* __restrict__ mval,
    float* __restrict__ pos_align,
    float* __restrict__ pos_ovl,
    float* __restrict__ out) {
    cg::grid_group grid = cg::this_grid();
    const int tid = threadIdx.x;
    const int lane = tid & 63, wid = tid >> 6;
    const int nb = gridDim.x;

    // ---------------- phase 0: init ----------------
    for (int i = blockIdx.x * 256 + tid; i < N_TOT; i += nb * 256) {
        fg[i] = 0;
        assignm[i] = 0x7FFFFFFF;
    }
    for (int i = blockIdx.x * 256 + tid; i < 2 * BS * NM; i += nb * 256)
        pos_align[i] = 0.f;  // covers pos_ovl too (contiguous)
    grid.sync();

    // ---------------- phase 1: topk (R6 body) ----------------
    __shared__ unsigned long long sheads[4 * TOPKK];
    __shared__ int sowner[4 * TOPKK];
    __shared__ int ssubmit[256];
    __shared__ unsigned long long spool[TOPKK * TPL];
    __shared__ int snpos;

    const int iters1 = (BS * NM + nb - 1) / nb;  // uniform across grid
    for (int it1 = 0; it1 < iters1; ++it1) {
        int bmx = blockIdx.x + it1 * nb;
        bool vbm = bmx < BS * NM;
        // XCD-aware swizzle (bijective: 2048 % 8 == 0)
        int bm = vbm ? (((bmx & 7) << 8) | (bmx >> 3)) : 0;
        bool active = vbm && (mask_gt[bm] > 0.f);

        const int b = bm / NM;
        const int m = bm - b * NM;
        const float4 g = ((const float4*)gt_bboxes)[bm];
        const int lbl = gt_labels[bm];
        const float4* pb = (const float4*)(pd_bboxes + (size_t)b * NA * 4);
        const float* ps = pd_scores + (size_t)b * NA * NC + lbl;

        const float w1 = g.z - g.x, h1 = g.w - g.y + 1e-7f;
        const float area1 = w1 * h1;
        const float at1 = atanf(w1 / h1);

        if (tid < 4 * TOPKK) sheads[tid] = 0ull;
        if (tid < TOPKK * TPL) spool[tid] = 0ull;
        ssubmit[tid] = -1;
        if (tid == 0) snpos = 0;
        __syncthreads();  // B0

        // tight per-level rects; zeroed when inactive (skips all loops)
        int c0_0, r0_0, w_0, cnt_0, c0_1, r0_1, w_1r, cnt_1, c0_2, r0_2, w_2, cnt_2;
        float iw_0, iw_1, iw_2;
#define MKRECT(NN, INVS, C0, R0, W, CNT, IW)                                   \
        {                                                                      \
            int c0 = (int)floorf(g.x * INVS - 0.5001f); if (c0 < 0) c0 = 0;    \
            int c1 = (int)ceilf (g.z * INVS - 0.4999f); if (c1 > NN - 1) c1 = NN - 1; \
            int r0 = (int)floorf(g.y * INVS - 0.5001f); if (r0 < 0) r0 = 0;    \
            int r1 = (int)ceilf (g.w * INVS - 0.4999f); if (r1 > NN - 1) r1 = NN - 1; \
            int w = c1 - c0 + 1; if (w < 0) w = 0;                             \
            int h = r1 - r0 + 1; if (h < 0) h = 0;                             \
            C0 = c0; R0 = r0; W = w; CNT = active ? w * h : 0;                 \
            IW = w > 0 ? 1.f / (float)w : 0.f;                                 \
        }
        MKRECT(80, 0.125f,   c0_0, r0_0, w_0,  cnt_0, iw_0)
        MKRECT(40, 0.0625f,  c0_1, r0_1, w_1r, cnt_1, iw_1)
        MKRECT(20, 0.03125f, c0_2, r0_2, w_2,  cnt_2, iw_2)
#undef MKRECT

        unsigned long long t0 = 0, t1 = 0, t2 = 0, t3 = 0,
                           t4 = 0, t5 = 0, t6 = 0, t7 = 0;

#define PROCESS(AX, AY, A)                                                     \
        {                                                                      \
            float dmin = fminf(fminf((AX) - g.x, (AY) - g.y),                  \
                               fminf(g.z - (AX), g.w - (AY)));                 \
            if (dmin > 1e-9f) { /* exact mask_in_gts (EPS = 1e-9) */           \
                float4 p = pb[A];                                              \
                float ov = ciou_clip_pre(g.x, g.y, g.z, g.w, area1, at1,       \
                                         p.x, p.y, p.z, p.w);                  \
                float sc = ps[(size_t)(A) * NC];                               \
                float ov2 = ov * ov;                                           \
                float metric = sc * ov2 * ov2 * ov2; /* score * overlap^6 */   \
                unsigned long long key =                                       \
                    ((unsigned long long)__float_as_uint(metric) << 32) |      \
                    (unsigned)(NA - 1 - (A));                                  \
                t7 = t6; t6 = t5; t5 = t4; t4 = t3;                            \
                t3 = t2; t2 = t1; t1 = t0; t0 = key;                           \
            }                                                                  \
        }
        for (int j = tid; j < cnt_0; j += 256) {
            int rr = (int)(((float)j + 0.5f) * iw_0);
            int cc = j - rr * w_0;
            int row = r0_0 + rr, col = c0_0 + cc;
            PROCESS(((float)col + 0.5f) * 8.f, ((float)row + 0.5f) * 8.f,
                    row * 80 + col)
        }
        for (int j = tid; j < cnt_1; j += 256) {
            int rr = (int)(((float)j + 0.5f) * iw_1);
            int cc = j - rr * w_1r;
            int row = r0_1 + rr, col = c0_1 + cc;
            PROCESS(((float)col + 0.5f) * 16.f, ((float)row + 0.5f) * 16.f,
                    6400 + row * 40 + col)
        }
        for (int j = tid; j < cnt_2; j += 256) {
            int rr = (int)(((float)j + 0.5f) * iw_2);
            int cc = j - rr * w_2;
            int row = r0_2 + rr, col = c0_2 + cc;
            PROCESS(((float)col + 0.5f) * 32.f, ((float)row + 0.5f) * 32.f,
                    8000 + row * 20 + col)
        }
#undef PROCESS

        // S1: per-wave head rank (readlane, register-only)
        {
            unsigned long long h =
                umax64(umax64(umax64(t0, t1), umax64(t2, t3)),
                       umax64(umax64(t4, t5), umax64(t6, t7)));
            unsigned hhi = (unsigned)(h >> 32), hlo = (unsigned)h;
            int wrank = 0;
#pragma unroll 8
            for (int l = 0; l < 64; ++l) {
                unsigned ohi = (unsigned)__builtin_amdgcn_readlane((int)hhi, l);
                unsigned olo = (unsigned)__builtin_amdgcn_readlane((int)hlo, l);
                wrank += (ohi > hhi) || (ohi == hhi && olo > hlo);
            }
            if (hhi != 0 && wrank < TOPKK) {
                sheads[wid * TOPKK + wrank] = h;
                sowner[wid * TOPKK + wrank] = tid;
            }
        }
        __syncthreads();  // B1

        // S2: wave 0 ranks the <=52 survivor heads
        if (wid == 0) {
            unsigned long long h2 = (lane < 4 * TOPKK) ? sheads[lane] : 0ull;
            unsigned h2hi = (unsigned)(h2 >> 32), h2lo = (unsigned)h2;
            int grank = 0;
#pragma unroll 4
            for (int l = 0; l < 4 * TOPKK; ++l) {
                unsigned ohi = (unsigned)__builtin_amdgcn_readlane((int)h2hi, l);
                unsigned olo = (unsigned)__builtin_amdgcn_readlane((int)h2lo, l);
                grank += (ohi > h2hi) || (ohi == h2hi && olo > h2lo);
            }
            if (lane < 4 * TOPKK && h2hi != 0 && grank < TOPKK)
                ssubmit[sowner[lane]] = grank;
        }
        __syncthreads();  // B2

        // S3: global survivors submit their positive keys to the pool
        {
            int s = ssubmit[tid];
            if (s >= 0) {
                unsigned long long* dst = &spool[s * TPL];
                if (t0 >> 32) dst[0] = t0;
                if (t1 >> 32) dst[1] = t1;
                if (t2 >> 32) dst[2] = t2;
                if (t3 >> 32) dst[3] = t3;
                if (t4 >> 32) dst[4] = t4;
                if (t5 >> 32) dst[5] = t5;
                if (t6 >> 32) dst[6] = t6;
                if (t7 >> 32) dst[7] = t7;
            }
        }
        __syncthreads();  // B3

        // S4: pool rank -> exact top-13 scatter
        if (tid < TOPKK * TPL) {
            unsigned long long key = spool[tid];
            if ((key >> 32) != 0ull) {
                int rank = 0;
                for (int j = 0; j < TOPKK * TPL; ++j) rank += spool[j] > key;
                if (rank < TOPKK) {
                    int a = NA - 1 - (int)(key & 0xFFFFFFFFull);
                    atomicAdd(&fg[b * NA + a], 1);
                    atomicMin(&assignm[b * NA + a], m);
                    atomicAdd(&snpos, 1);
                }
            }
        }
        __syncthreads();  // B4

        // S5: fillers (smallest-index zero-metric anchors, indices 0..63)
        if (wid == 0 && active) {
            int nf = TOPKK - snpos;
            if (nf > 0) {
                int f = lane;
                float ax = ((float)f + 0.5f) * 8.f, ay = 4.0f;
                float dmin = fminf(fminf(ax - g.x, ay - g.y),
                                   fminf(g.z - ax, g.w - ay));
                bool inbox = dmin > 1e-9f;
                float metric = 0.f;
                if (inbox) {
                    float4 p = pb[f];
                    float ov = ciou_clip_pre(g.x, g.y, g.z, g.w, area1, at1,
                                             p.x, p.y, p.z, p.w);
                    float ov2 = ov * ov;
                    metric = ps[(size_t)f * NC] * ov2 * ov2 * ov2;
                }
                bool pos = inbox && (metric > 0.f);
                unsigned long long pmask = __ballot(pos);
                if (inbox && !pos) {
                    int rank = __popcll(~pmask & ((1ull << f) - 1ull));
                    if (rank < nf) {
                        atomicAdd(&fg[b * NA + f], 1);
                        atomicMin(&assignm[b * NA + f], m);
                    }
                }
            }
        }
        __syncthreads();  // B5: protect LDS reuse by next iteration
    }
    grid.sync();

    // ---------------- phase 2: assign (R6 body) ----------------
    for (int i = blockIdx.x * 256 + tid; i < N_TOT; i += nb * 256) {
        int b = i / NA, a = i - b * NA;
        int f = fg[i];
        if (f <= 0) {
            fg[i] = 0;
            assignm[i] = 0;  // argmax of all-zero column = 0
            mval[i] = 0.f;
            continue;
        }
        float ax, ay;
        anchor_xy(a, ax, ay);
        float4 p = ((const float4*)pd_bboxes)[i];

        int m;
        if (f == 1) {
            m = assignm[i];
        } else {
            // multi: one_hot(argmax_m overlaps[b,:,a]); ties -> first m
            float best = -1.f;
            int bestm = 0;
            for (int mm = 0; mm < NM; ++mm) {
                float4 gg = ((const float4*)gt_bboxes)[b * NM + mm];
                float dmin = fminf(fminf(ax - gg.x, ay - gg.y),
                                   fminf(gg.z - ax, gg.w - ay));
                float ov = 0.f;
                if (dmin > 1e-9f && mask_gt[b * NM + mm] > 0.f) {
                    float w1 = gg.z - gg.x, h1 = gg.w - gg.y + 1e-7f;
                    ov = ciou_clip_pre(gg.x, gg.y, gg.z, gg.w, w1 * h1,
                                       atanf(w1 / h1), p.x, p.y, p.z, p.w);
                }
                if (ov > best) { best = ov; bestm = mm; }
            }
            m = bestm;
        }

        float4 gg = ((const float4*)gt_bboxes)[b * NM + m];
        float dmin = fminf(fminf(ax - gg.x, ay - gg.y),
                           fminf(gg.z - ax, gg.w - ay));
        float mv = 0.f, ovv = 0.f;
        if (dmin > 1e-9f && mask_gt[b * NM + m] > 0.f) {
            float w1 = gg.z - gg.x, h1 = gg.w - gg.y + 1e-7f;
            ovv = ciou_clip_pre(gg.x, gg.y, gg.z, gg.w, w1 * h1,
                                atanf(w1 / h1), p.x, p.y, p.z, p.w);
            float s = pd_scores[(size_t)i * NC + gt_labels[b * NM + m]];
            float ov2 = ovv * ovv;
            mv = s * ov2 * ov2 * ov2;
        }
        fg[i] = 1;
        assignm[i] = m;
        mval[i] = mv;
        // values >= 0 -> int compare == float compare; order-independent.
        atomicMax((int*)&pos_align[b * NM + m], __float_as_int(mv));
        atomicMax((int*)&pos_ovl[b * NM + m], __float_as_int(ovv));
    }
    grid.sync();

    // ---------------- phase 3: fused final + scores (R6 body) --------------
    __shared__ int   slbl[256];
    __shared__ float snrm[256];
    const int nchunk = (N_TOT + 255) / 256;        // 1050
    const int iters3 = (nchunk + nb - 1) / nb;     // uniform
    for (int it3 = 0; it3 < iters3; ++it3) {
        int chunk = blockIdx.x + it3 * nb;
        bool cval = chunk < nchunk;
        int i = chunk * 256 + tid;

        if (cval && i < N_TOT) {
            int b = i / NA;
            int m = assignm[i];
            int f = fg[i];
            int lbl = gt_labels[b * NM + m];
            lbl = lbl < 0 ? 0 : lbl;
            float4 box = ((const float4*)gt_bboxes)[b * NM + m];
            float nrm = 0.f;
            if (f) nrm = mval[i] * pos_ovl[b * NM + m] /
                         (pos_align[b * NM + m] + 1e-9f);
            out[i] = (float)lbl;                          // target_labels
            ((float4*)(out + N_TOT))[i] = box;            // target_bboxes
            out[(size_t)85 * N_TOT + i] = f ? 1.f : 0.f;  // fg_mask
            out[(size_t)86 * N_TOT + i] = (float)m;       // target_gt_idx
            slbl[tid] = f ? lbl : -1;
            snrm[tid] = nrm;
        }
        __syncthreads();

        if (cval) {
            float4* out4 = (float4*)(out + (size_t)5 * N_TOT) +
                           (size_t)chunk * 256 * (NC / 4);
            const int base_anchor = chunk * 256;
#pragma unroll
            for (int itc = 0; itc < NC / 4; ++itc) {
                int j = itc * 256 + tid;
                int il = j / (NC / 4);
                if (base_anchor + il >= N_TOT) break;
                int c0 = (j - il * (NC / 4)) * 4;
                int lbl = slbl[il];
                float4 v = make_float4(0.f, 0.f, 0.f, 0.f);
                if (lbl >= c0 && lbl < c0 + 4) {
                    float n = snrm[il];
                    if (lbl == c0) v.x = n;
                    else if (lbl == c0 + 1) v.y = n;
                    else if (lbl == c0 + 2) v.z = n;
                    else v.w = n;
                }
                out4[j] = v;
            }
        }
        __syncthreads();  // protect slbl/snrm reuse by next iteration
    }
}

// ===================== FALLBACK: R6 4-kernel sequence =======================
__global__ __launch_bounds__(256) void k_init(int* __restrict__ fg,
                                              int* __restrict__ assignm,
                                              float* __restrict__ pos) {
    int i = blockIdx.x * blockDim.x + threadIdx.x;
    if (i < N_TOT) {
        fg[i] = 0;
        assignm[i] = 0x7FFFFFFF;
    }
    if (i < 2 * BS * NM) pos[i] = 0.f;
}

__global__ __launch_bounds__(256) void k_topk(
    const float* __restrict__ pd_scores,
    const float* __restrict__ pd_bboxes,
    const int* __restrict__ gt_labels,
    const float* __restrict__ gt_bboxes,
    const float* __restrict__ mask_gt,
    int* __restrict__ fg,
    int* __restrict__ assignm) {
    const int bm = ((blockIdx.x & 7) << 8) | (blockIdx.x >> 3);
    if (mask_gt[bm] <= 0.f) return;

    const int tid = threadIdx.x;
    const int lane = tid & 63, wid = tid >> 6;
    const int b = bm / NM;
    const int m = bm - b * NM;
    const float4 g = ((const float4*)gt_bboxes)[bm];
    const float4* pb = (const float4*)(pd_bboxes + (size_t)b * NA * 4);
    const float* ps = pd_scores + (size_t)b * NA * NC + gt_labels[bm];

    const float w1 = g.z - g.x, h1 = g.w - g.y + 1e-7f;
    const float area1 = w1 * h1;
    const float at1 = atanf(w1 / h1);

    __shared__ unsigned long long sheads[4 * TOPKK];
    __shared__ int sowner[4 * TOPKK];
    __shared__ int ssubmit[256];
    __shared__ unsigned long long spool[TOPKK * TPL];
    __shared__ int snpos;

    if (tid < 4 * TOPKK) sheads[tid] = 0ull;
    if (tid < TOPKK * TPL) spool[tid] = 0ull;
    ssubmit[tid] = -1;
    if (tid == 0) snpos = 0;
    __syncthreads();

    int c0_0, r0_0, w_0, cnt_0, c0_1, r0_1, w_1r, cnt_1, c0_2, r0_2, w_2, cnt_2;
    float iw_0, iw_1, iw_2;
#define MKRECT(NN, INVS, C0, R0, W, CNT, IW)                                   \
    {                                                                          \
        int c0 = (int)floorf(g.x * INVS - 0.5001f); if (c0 < 0) c0 = 0;        \
        int c1 = (int)ceilf (g.z * INVS - 0.4999f); if (c1 > NN - 1) c1 = NN - 1; \
        int r0 = (int)floorf(g.y * INVS - 0.5001f); if (r0 < 0) r0 = 0;        \
        int r1 = (int)ceilf (g.w * INVS - 0.4999f); if (r1 > NN - 1) r1 = NN - 1; \
        int w = c1 - c0 + 1; if (w < 0) w = 0;                                 \
        int h = r1 - r0 + 1; if (h < 0) h = 0;                                 \
        C0 = c0; R0 = r0; W = w; CNT = w * h; IW = w > 0 ? 1.f / (float)w : 0.f; \
    }
    MKRECT(80, 0.125f,   c0_0, r0_0, w_0,  cnt_0, iw_0)
    MKRECT(40, 0.0625f,  c0_1, r0_1, w_1r, cnt_1, iw_1)
    MKRECT(20, 0.03125f, c0_2, r0_2, w_2,  cnt_2, iw_2)
#undef MKRECT

    unsigned long long t0 = 0, t1 = 0, t2 = 0, t3 = 0,
                       t4 = 0, t5 = 0, t6 = 0, t7 = 0;

#define PROCESS(AX, AY, A)                                                     \
    {                                                                          \
        float dmin = fminf(fminf((AX) - g.x, (AY) - g.y),                      \
                           fminf(g.z - (AX), g.w - (AY)));                     \
        if (dmin > 1e-9f) {                                                    \
            float4 p = pb[A];                                                  \
            float ov = ciou_clip_pre(g.x, g.y, g.z, g.w, area1, at1,           \
                                     p.x, p.y, p.z, p.w);                      \
            float sc = ps[(size_t)(A) * NC];                                   \
            float ov2 = ov * ov;                                               \
            float metric = sc * ov2 * ov2 * ov2;                               \
            unsigned long long key =                                           \
                ((unsigned long long)__float_as_uint(metric) << 32) |          \
                (unsigned)(NA - 1 - (A));                                      \
            t7 = t6; t6 = t5; t5 = t4; t4 = t3;                                \
            t3 = t2; t2 = t1; t1 = t0; t0 = key;                               \
        }                                                                      \
    }
    for (int j = tid; j < cnt_0; j += 256) {
        int rr = (int)(((float)j + 0.5f) * iw_0);
        int cc = j - rr * w_0;
        int row = r0_0 + rr, col = c0_0 + cc;
        PROCESS(((float)col + 0.5f) * 8.f, ((float)row + 0.5f) * 8.f,
                row * 80 + col)
    }
    for (int j = tid; j < cnt_1; j += 256) {
        int rr = (int)(((float)j + 0.5f) * iw_1);
        int cc = j - rr * w_1r;
        int row = r0_1 + rr, col = c0_1 + cc;
        PROCESS(((float)col + 0.5f) * 16.f, ((float)row + 0.5f) * 16.f,
                6400 + row * 40 + col)
    }
    for (int j = tid; j < cnt_2; j += 256) {
        int rr = (int)(((float)j + 0.5f) * iw_2);
        int cc = j - rr * w_2;
        int row = r0_2 + rr, col = c0_2 + cc;
        PROCESS(((float)col + 0.5f) * 32.f, ((float)row + 0.5f) * 32.f,
                8000 + row * 20 + col)
    }
#undef PROCESS

    {
        unsigned long long h =
            umax64(umax64(umax64(t0, t1), umax64(t2, t3)),
                   umax64(umax64(t4, t5), umax64(t6, t7)));
        unsigned hhi = (unsigned)(h >> 32), hlo = (unsigned)h;
        int wrank = 0;
#pragma unroll 8
        for (int l = 0; l < 64; ++l) {
            unsigned ohi = (unsigned)__builtin_amdgcn_readlane((int)hhi, l);
            unsigned olo = (unsigned)__builtin_amdgcn_readlane((int)hlo, l);
            wrank += (ohi > hhi) || (ohi == hhi && olo > hlo);
        }
        if (hhi != 0 && wrank < TOPKK) {
            sheads[wid * TOPKK + wrank] = h;
            sowner[wid * TOPKK + wrank] = tid;
        }
    }
    __syncthreads();

    if (wid == 0) {
        unsigned long long h2 = (lane < 4 * TOPKK) ? sheads[lane] : 0ull;
        unsigned h2hi = (unsigned)(h2 >> 32), h2lo = (unsigned)h2;
        int grank = 0;
#pragma unroll 4
        for (int l = 0; l < 4 * TOPKK; ++l) {
            unsigned ohi = (unsigned)__builtin_amdgcn_readlane((int)h2hi, l);
            unsigned olo = (unsigned)__builtin_amdgcn_readlane((int)h2lo, l);
            grank += (ohi > h2hi) || (ohi == h2hi && olo > h2lo);
        }
        if (lane < 4 * TOPKK && h2hi != 0 && grank < TOPKK)
            ssubmit[sowner[lane]] = grank;
    }
    __syncthreads();

    {
        int s = ssubmit[tid];
        if (s >= 0) {
            unsigned long long* dst = &spool[s * TPL];
            if (t0 >> 32) dst[0] = t0;
            if (t1 >> 32) dst[1] = t1;
            if (t2 >> 32) dst[2] = t2;
            if (t3 >> 32) dst[3] = t3;
            if (t4 >> 32) dst[4] = t4;
            if (t5 >> 32) dst[5] = t5;
            if (t6 >> 32) dst[6] = t6;
            if (t7 >> 32) dst[7] = t7;
        }
    }
    __syncthreads();

    if (tid < TOPKK * TPL) {
        unsigned long long key = spool[tid];
        if ((key >> 32) != 0ull) {
            int rank = 0;
            for (int j = 0; j < TOPKK * TPL; ++j) rank += spool[j] > key;
            if (rank < TOPKK) {
                int a = NA - 1 - (int)(key & 0xFFFFFFFFull);
                atomicAdd(&fg[b * NA + a], 1);
                atomicMin(&assignm[b * NA + a], m);
                atomicAdd(&snpos, 1);
            }
        }
    }
    __syncthreads();

    if (wid == 0) {
        int nf = TOPKK - snpos;
        if (nf > 0) {
            int f = lane;
            float ax = ((float)f + 0.5f) * 8.f, ay = 4.0f;
            float dmin = fminf(fminf(ax - g.x, ay - g.y),
                               fminf(g.z - ax, g.w - ay));
            bool inbox = dmin > 1e-9f;
            float metric = 0.f;
            if (inbox) {
                float4 p = pb[f];
                float ov = ciou_clip_pre(g.x, g.y, g.z, g.w, area1, at1,
                                         p.x, p.y, p.z, p.w);
                float ov2 = ov * ov;
                metric = ps[(size_t)f * NC] * ov2 * ov2 * ov2;
            }
            bool pos = inbox && (metric > 0.f);
            unsigned long long pmask = __ballot(pos);
            if (inbox && !pos) {
                int rank = __popcll(~pmask & ((1ull << f) - 1ull));
                if (rank < nf) {
                    atomicAdd(&fg[b * NA + f], 1);
                    atomicMin(&assignm[b * NA + f], m);
                }
            }
        }
    }
}

__global__ __launch_bounds__(256) void k_assign(
    const float* __restrict__ pd_scores,
    const float* __restrict__ pd_bboxes,
    const int* __restrict__ gt_labels,
    const float* __restrict__ gt_bboxes,
    const float* __restrict__ mask_gt,
    int* fg_inout, int* assign_inout,
    float* __restrict__ mval,
    float* __restrict__ pos_align,
    float* __restrict__ pos_ovl) {
    int i = blockIdx.x * blockDim.x + threadIdx.x;
    if (i >= N_TOT) return;
    int b = i / NA, a = i - b * NA;

    int f = fg_inout[i];
    if (f <= 0) {
        fg_inout[i] = 0;
        assign_inout[i] = 0;
        mval[i] = 0.f;
        return;
    }
    float ax, ay;
    anchor_xy(a, ax, ay);
    float4 p = ((const float4*)pd_bboxes)[i];

    int m;
    if (f == 1) {
        m = assign_inout[i];
    } else {
        float best = -1.f;
        int bestm = 0;
        for (int mm = 0; mm < NM; ++mm) {
            float4 gg = ((const float4*)gt_bboxes)[b * NM + mm];
            float dmin = fminf(fminf(ax - gg.x, ay - gg.y),
                               fminf(gg.z - ax, gg.w - ay));
            float ov = 0.f;
            if (dmin > 1e-9f && mask_gt[b * NM + mm] > 0.f) {
                float w1 = gg.z - gg.x, h1 = gg.w - gg.y + 1e-7f;
                ov = ciou_clip_pre(gg.x, gg.y, gg.z, gg.w, w1 * h1,
                                   atanf(w1 / h1), p.x, p.y, p.z, p.w);
            }
            if (ov > best) { best = ov; bestm = mm; }
        }
        m = bestm;
    }

    float4 gg = ((const float4*)gt_bboxes)[b * NM + m];
    float dmin = fminf(fminf(ax - gg.x, ay - gg.y), fminf(gg.z - ax, gg.w - ay));
    float mv = 0.f, ovv = 0.f;
    if (dmin > 1e-9f && mask_gt[b * NM + m] > 0.f) {
        float w1 = gg.z - gg.x, h1 = gg.w - gg.y + 1e-7f;
        ovv = ciou_clip_pre(gg.x, gg.y, gg.z, gg.w, w1 * h1, atanf(w1 / h1),
                            p.x, p.y, p.z, p.w);
        float s = pd_scores[(size_t)i * NC + gt_labels[b * NM + m]];
        float ov2 = ovv * ovv;
        mv = s * ov2 * ov2 * ov2;
    }
    fg_inout[i] = 1;
    assign_inout[i] = m;
    mval[i] = mv;
    atomicMax((int*)&pos_align[b * NM + m], __float_as_int(mv));
    atomicMax((int*)&pos_ovl[b * NM + m], __float_as_int(ovv));
}

__global__ __launch_bounds__(256) void k_fused(
    const int* __restrict__ gt_labels,
    const float* __restrict__ gt_bboxes,
    const int* __restrict__ fgm,
    const int* __restrict__ tgt,
    const float* __restrict__ mval,
    const float* __restrict__ pos_align,
    const float* __restrict__ pos_ovl,
    float* __restrict__ out) {
    __shared__ int   slbl[256];
    __shared__ float snrm[256];
    const int tid = threadIdx.x;
    const int i = blockIdx.x * 256 + tid;

    if (i < N_TOT) {
        int b = i / NA;
        int m = tgt[i];
        int f = fgm[i];
        int lbl = gt_labels[b * NM + m];
        lbl = lbl < 0 ? 0 : lbl;
        float4 box = ((const float4*)gt_bboxes)[b * NM + m];
        float nrm = 0.f;
        if (f) nrm = mval[i] * pos_ovl[b * NM + m] / (pos_align[b * NM + m] + 1e-9f);
        out[i] = (float)lbl;
        ((float4*)(out + N_TOT))[i] = box;
        out[(size_t)85 * N_TOT + i] = f ? 1.f : 0.f;
        out[(size_t)86 * N_TOT + i] = (float)m;
        slbl[tid] = f ? lbl : -1;
        snrm[tid] = nrm;
    }
    __syncthreads();

    float4* out4 = (float4*)(out + (size_t)5 * N_TOT) + (size_t)blockIdx.x * 256 * (NC / 4);
    const int base_anchor = blockIdx.x * 256;
#pragma unroll
    for (int it = 0; it < NC / 4; ++it) {
        int j = it * 256 + tid;
        int il = j / (NC / 4);
        if (base_anchor + il >= N_TOT) break;
        int c0 = (j - il * (NC / 4)) * 4;
        int lbl = slbl[il];
        float4 v = make_float4(0.f, 0.f, 0.f, 0.f);
        if (lbl >= c0 && lbl < c0 + 4) {
            float n = snrm[il];
            if (lbl == c0) v.x = n;
            else if (lbl == c0 + 1) v.y = n;
            else if (lbl == c0 + 2) v.z = n;
            else v.w = n;
        }
        out4[j] = v;
    }
}

extern "C" void kernel_launch(void* const* d_in, const int* in_sizes, int n_in,
                              void* d_out, int out_size, void* d_ws, size_t ws_size,
                              hipStream_t stream) {
    const float* pd_scores = (const float*)d_in[0];
    const float* pd_bboxes = (const float*)d_in[1];
    const int*   gt_labels = (const int*)d_in[3];
    // d_in[2] = anc_points (recomputed in-register), d_in[4] = gt_scores: unused
    const float* gt_bboxes = (const float*)d_in[5];
    const float* mask_gt   = (const float*)d_in[6];
    float* out = (float*)d_out;

    char* ws = (char*)d_ws;
    int*   fg        = (int*)ws;                          // N_TOT i32
    int*   assignm   = (int*)(ws + 4 * (size_t)N_TOT);    // N_TOT i32
    float* mval      = (float*)(ws + 8 * (size_t)N_TOT);  // N_TOT f32
    float* pos_align = (float*)(ws + 12 * (size_t)N_TOT); // BS*NM f32
    float* pos_ovl   = pos_align + BS * NM;               // BS*NM f32

    // cooperative mega-kernel (1024 blocks co-resident by __launch_bounds__)
    void* args[] = {
        (void*)&pd_scores, (void*)&pd_bboxes, (void*)&gt_labels,
        (void*)&gt_bboxes, (void*)&mask_gt,
        (void*)&fg, (void*)&assignm, (void*)&mval,
        (void*)&pos_align, (void*)&pos_ovl, (void*)&out
    };
    hipError_t err = hipLaunchCooperativeKernel(
        (const void*)k_mega, dim3(1024), dim3(256), args, 0, stream);

    if (err != hipSuccess) {
        // fallback: R6 4-kernel sequence (identical semantics)
        int nb = (N_TOT + 255) / 256;
        k_init<<<nb, 256, 0, stream>>>(fg, assignm, pos_align);
        k_topk<<<BS * NM, 256, 0, stream>>>(pd_scores, pd_bboxes, gt_labels,
                                            gt_bboxes, mask_gt, fg, assignm);
        k_assign<<<nb, 256, 0, stream>>>(pd_scores, pd_bboxes, gt_labels,
                                         gt_bboxes, mask_gt, fg, assignm, mval,
                                         pos_align, pos_ovl);
        k_fused<<<nb, 256, 0, stream>>>(gt_labels, gt_bboxes, fg, assignm, mval,
                                        pos_align, pos_ovl, out);
    }
}

// Round 11
// 78.277 us; speedup vs baseline: 4.8682x; 4.8682x over previous
//
#include <hip/hip_runtime.h>
#include <math.h>

#define BS 32
#define NM 64
#define NA 8400
#define NC 80
#define TOPKK 13
#define N_TOT (BS * NA)
#define TPL 8  // per-lane candidate bound: ceil(1156/256)+ceil(324/256)+1 = 8

// CIoU (box1 = gt, box2 = pred) with gt-side terms hoisted; clipped at 0.
// Bit-identical to the reference _ciou (eps=1e-7) + jnp.clip(x, 0).
__device__ __forceinline__ float ciou_clip_pre(
    float gx1, float gy1, float gx2, float gy2,
    float area1, float at1,
    float px1, float py1, float px2, float py2) {
    const float eps = 1e-7f;
    float w2 = px2 - px1, h2 = py2 - py1 + eps;
    float iw = fmaxf(fminf(gx2, px2) - fmaxf(gx1, px1), 0.f);
    float ih = fmaxf(fminf(gy2, py2) - fmaxf(gy1, py1), 0.f);
    float inter = iw * ih;
    float uni = area1 + w2 * h2 - inter + eps;
    float iou = inter / uni;
    float cw = fmaxf(gx2, px2) - fminf(gx1, px1);
    float ch = fmaxf(gy2, py2) - fminf(gy1, py1);
    float c2 = cw * cw + ch * ch + eps;
    float dx = px1 + px2 - gx1 - gx2;
    float dy = py1 + py2 - gy1 - gy2;
    float rho2 = (dx * dx + dy * dy) * 0.25f;
    float dat = atanf(w2 / h2) - at1;
    float v = 0.4052847345693511f * dat * dat;  // 4/pi^2
    float al = v / (v - iou + 1.0000001f);      // 1.0 + eps
    return fmaxf(iou - (rho2 / c2 + v * al), 0.f);
}

__device__ __forceinline__ unsigned long long umax64(unsigned long long a,
                                                     unsigned long long b) {
    return a > b ? a : b;
}

// anchor index -> (ax, ay) exactly: (i+0.5)*stride, bit-identical to reference.
__device__ __forceinline__ void anchor_xy(int a, float& ax, float& ay) {
    int loc, n; float s;
    if (a < 6400)      { loc = a;        n = 80; s = 8.f;  }
    else if (a < 8000) { loc = a - 6400; n = 40; s = 16.f; }
    else               { loc = a - 8000; n = 20; s = 32.f; }
    int row = loc / n, col = loc - row * n;
    ax = ((float)col + 0.5f) * s;
    ay = ((float)row + 0.5f) * s;
}

__global__ __launch_bounds__(256) void k_init(int* __restrict__ fg,
                                              int* __restrict__ assignm,
                                              float* __restrict__ pos) {
    int i = blockIdx.x * blockDim.x + threadIdx.x;
    if (i < N_TOT) {
        fg[i] = 0;
        assignm[i] = 0x7FFFFFFF;
    }
    if (i < 2 * BS * NM) pos[i] = 0.f;
}

// Kernel 1 (R6 structure, best measured): one 256-thread block per (b, m).
// Tight rect candidates (~450), three wave-uniform per-level scan loops, one
// atanf per candidate (gt-side hoisted), shift-register capture (per-lane
// count <= 8, capture-complete), rank-prune tail:
//   S1 per-wave head-rank (readlane) -> <=13 survivors/wave
//   S2 wave 0 ranks <=52 heads -> <=13 global survivors w/ pool slots
//   S3 survivors submit positive keys to <=104-entry LDS pool
//   S4 pool-rank; rank<13 <=> exact jax.lax.top_k top-13 -> scatter
//   S5 exact zero-metric filler via 64-lane ballot (nf = 13 - npos)
// Score gather uses nontemporal loads: score lines are used ~once per
// dispatch; bypassing L2 preserves the reused per-batch bbox panel.
__global__ __launch_bounds__(256) void k_topk(
    const float* __restrict__ pd_scores,
    const float* __restrict__ pd_bboxes,
    const int* __restrict__ gt_labels,
    const float* __restrict__ gt_bboxes,
    const float* __restrict__ mask_gt,
    int* __restrict__ fg,
    int* __restrict__ assignm) {
    // XCD-aware swizzle (bijective: 2048 % 8 == 0)
    const int bm = ((blockIdx.x & 7) << 8) | (blockIdx.x >> 3);
    if (mask_gt[bm] <= 0.f) return;  // row contributes nothing (count=13@idx0)

    const int tid = threadIdx.x;
    const int lane = tid & 63, wid = tid >> 6;
    const int b = bm / NM;
    const int m = bm - b * NM;
    const float4 g = ((const float4*)gt_bboxes)[bm];
    const int lbl = gt_labels[bm];
    const float4* pb = (const float4*)(pd_bboxes + (size_t)b * NA * 4);
    const float* ps = pd_scores + (size_t)b * NA * NC + lbl;

    // gt-side CIoU invariants (block-uniform)
    const float w1 = g.z - g.x, h1 = g.w - g.y + 1e-7f;
    const float area1 = w1 * h1;
    const float at1 = atanf(w1 / h1);

    __shared__ unsigned long long sheads[4 * TOPKK];
    __shared__ int sowner[4 * TOPKK];
    __shared__ int ssubmit[256];
    __shared__ unsigned long long spool[TOPKK * TPL];
    __shared__ int snpos;

    if (tid < 4 * TOPKK) sheads[tid] = 0ull;
    if (tid < TOPKK * TPL) spool[tid] = 0ull;
    ssubmit[tid] = -1;
    if (tid == 0) snpos = 0;
    __syncthreads();  // B0

    // tight per-level rects (1e-4 margin; exact dmin test is the real filter)
    int c0_0, r0_0, w_0, cnt_0, c0_1, r0_1, w_1r, cnt_1, c0_2, r0_2, w_2, cnt_2;
    float iw_0, iw_1, iw_2;
#define MKRECT(NN, INVS, C0, R0, W, CNT, IW)                                   \
    {                                                                          \
        int c0 = (int)floorf(g.x * INVS - 0.5001f); if (c0 < 0) c0 = 0;        \
        int c1 = (int)ceilf (g.z * INVS - 0.4999f); if (c1 > NN - 1) c1 = NN - 1; \
        int r0 = (int)floorf(g.y * INVS - 0.5001f); if (r0 < 0) r0 = 0;        \
        int r1 = (int)ceilf (g.w * INVS - 0.4999f); if (r1 > NN - 1) r1 = NN - 1; \
        int w = c1 - c0 + 1; if (w < 0) w = 0;                                 \
        int h = r1 - r0 + 1; if (h < 0) h = 0;                                 \
        C0 = c0; R0 = r0; W = w; CNT = w * h; IW = w > 0 ? 1.f / (float)w : 0.f; \
    }
    MKRECT(80, 0.125f,   c0_0, r0_0, w_0,  cnt_0, iw_0)
    MKRECT(40, 0.0625f,  c0_1, r0_1, w_1r, cnt_1, iw_1)
    MKRECT(20, 0.03125f, c0_2, r0_2, w_2,  cnt_2, iw_2)
#undef MKRECT

    // shift-register candidate capture (named slots: static indexing only)
    unsigned long long t0 = 0, t1 = 0, t2 = 0, t3 = 0,
                       t4 = 0, t5 = 0, t6 = 0, t7 = 0;

#define PROCESS(AX, AY, A)                                                     \
    {                                                                          \
        float dmin = fminf(fminf((AX) - g.x, (AY) - g.y),                      \
                           fminf(g.z - (AX), g.w - (AY)));                     \
        if (dmin > 1e-9f) { /* exact mask_in_gts (EPS = 1e-9) */               \
            float4 p = pb[A];                                                  \
            float ov = ciou_clip_pre(g.x, g.y, g.z, g.w, area1, at1,           \
                                     p.x, p.y, p.z, p.w);                      \
            float sc = __builtin_nontemporal_load(&ps[(size_t)(A) * NC]);      \
            float ov2 = ov * ov;                                               \
            float metric = sc * ov2 * ov2 * ov2; /* score * overlap^6 */       \
            unsigned long long key =                                           \
                ((unsigned long long)__float_as_uint(metric) << 32) |          \
                (unsigned)(NA - 1 - (A));                                      \
            t7 = t6; t6 = t5; t5 = t4; t4 = t3;                                \
            t3 = t2; t2 = t1; t1 = t0; t0 = key;                               \
        }                                                                      \
    }

    for (int j = tid; j < cnt_0; j += 256) {  // level 0: stride 8, n=80
        int rr = (int)(((float)j + 0.5f) * iw_0);
        int cc = j - rr * w_0;
        int row = r0_0 + rr, col = c0_0 + cc;
        PROCESS(((float)col + 0.5f) * 8.f, ((float)row + 0.5f) * 8.f,
                row * 80 + col)
    }
    for (int j = tid; j < cnt_1; j += 256) {  // level 1: stride 16, n=40
        int rr = (int)(((float)j + 0.5f) * iw_1);
        int cc = j - rr * w_1r;
        int row = r0_1 + rr, col = c0_1 + cc;
        PROCESS(((float)col + 0.5f) * 16.f, ((float)row + 0.5f) * 16.f,
                6400 + row * 40 + col)
    }
    for (int j = tid; j < cnt_2; j += 256) {  // level 2: stride 32, n=20
        int rr = (int)(((float)j + 0.5f) * iw_2);
        int cc = j - rr * w_2;
        int row = r0_2 + rr, col = c0_2 + cc;
        PROCESS(((float)col + 0.5f) * 32.f, ((float)row + 0.5f) * 32.f,
                8000 + row * 20 + col)
    }
#undef PROCESS

    // S1: per-wave head rank (readlane loop — register-only)
    {
        unsigned long long h =
            umax64(umax64(umax64(t0, t1), umax64(t2, t3)),
                   umax64(umax64(t4, t5), umax64(t6, t7)));
        unsigned hhi = (unsigned)(h >> 32), hlo = (unsigned)h;
        int wrank = 0;
#pragma unroll 8
        for (int l = 0; l < 64; ++l) {
            unsigned ohi = (unsigned)__builtin_amdgcn_readlane((int)hhi, l);
            unsigned olo = (unsigned)__builtin_amdgcn_readlane((int)hlo, l);
            wrank += (ohi > hhi) || (ohi == hhi && olo > hlo);
        }
        if (hhi != 0 && wrank < TOPKK) {
            sheads[wid * TOPKK + wrank] = h;
            sowner[wid * TOPKK + wrank] = tid;
        }
    }
    __syncthreads();  // B1

    // S2: wave 0 ranks the <=52 survivor heads
    if (wid == 0) {
        unsigned long long h2 = (lane < 4 * TOPKK) ? sheads[lane] : 0ull;
        unsigned h2hi = (unsigned)(h2 >> 32), h2lo = (unsigned)h2;
        int grank = 0;
#pragma unroll 4
        for (int l = 0; l < 4 * TOPKK; ++l) {
            unsigned ohi = (unsigned)__builtin_amdgcn_readlane((int)h2hi, l);
            unsigned olo = (unsigned)__builtin_amdgcn_readlane((int)h2lo, l);
            grank += (ohi > h2hi) || (ohi == h2hi && olo > h2lo);
        }
        if (lane < 4 * TOPKK && h2hi != 0 && grank < TOPKK)
            ssubmit[sowner[lane]] = grank;
    }
    __syncthreads();  // B2

    // S3: global survivors submit their positive keys to the pool
    {
        int s = ssubmit[tid];
        if (s >= 0) {
            unsigned long long* dst = &spool[s * TPL];
            if (t0 >> 32) dst[0] = t0;
            if (t1 >> 32) dst[1] = t1;
            if (t2 >> 32) dst[2] = t2;
            if (t3 >> 32) dst[3] = t3;
            if (t4 >> 32) dst[4] = t4;
            if (t5 >> 32) dst[5] = t5;
            if (t6 >> 32) dst[6] = t6;
            if (t7 >> 32) dst[7] = t7;
        }
    }
    __syncthreads();  // B3

    // S4: pool rank (broadcast LDS reads) -> exact top-13 scatter
    if (tid < TOPKK * TPL) {
        unsigned long long key = spool[tid];
        if ((key >> 32) != 0ull) {
            int rank = 0;
            for (int j = 0; j < TOPKK * TPL; ++j) rank += spool[j] > key;
            if (rank < TOPKK) {
                int a = NA - 1 - (int)(key & 0xFFFFFFFFull);
                atomicAdd(&fg[b * NA + a], 1);
                atomicMin(&assignm[b * NA + a], m);
                atomicAdd(&snpos, 1);
            }
        }
    }
    __syncthreads();  // B4

    // S5: fillers — remaining 13-npos slots = smallest-index zero-metric
    // anchors (provably within indices 0..63). In-box fillers scatter.
    if (wid == 0) {
        int nf = TOPKK - snpos;
        if (nf > 0) {
            int f = lane;  // anchor f: level-0 row 0 -> ax=(f+0.5)*8, ay=4
            float ax = ((float)f + 0.5f) * 8.f, ay = 4.0f;
            float dmin = fminf(fminf(ax - g.x, ay - g.y),
                               fminf(g.z - ax, g.w - ay));
            bool inbox = dmin > 1e-9f;
            float metric = 0.f;
            if (inbox) {
                float4 p = pb[f];
                float ov = ciou_clip_pre(g.x, g.y, g.z, g.w, area1, at1,
                                         p.x, p.y, p.z, p.w);
                float ov2 = ov * ov;
                metric = ps[(size_t)f * NC] * ov2 * ov2 * ov2;
            }
            bool pos = inbox && (metric > 0.f);
            unsigned long long pmask = __ballot(pos);
            if (inbox && !pos) {
                int rank = __popcll(~pmask & ((1ull << f) - 1ull));
                if (rank < nf) {
                    atomicAdd(&fg[b * NA + f], 1);
                    atomicMin(&assignm[b * NA + f], m);
                }
            }
        }
    }
}

// Kernel 2: one thread per (b, a). Resolve multi-assignment via masked-overlap
// argmax (tie -> lowest m), recompute assigned metric/overlap, reduce
// pos_align/pos_ovl per (b, m). Pred-side atanf hoisted out of the gt loop.
__global__ __launch_bounds__(256) void k_assign(
    const float* __restrict__ pd_scores,
    const float* __restrict__ pd_bboxes,
    const int* __restrict__ gt_labels,
    const float* __restrict__ gt_bboxes,
    const float* __restrict__ mask_gt,
    int* fg_inout,      // in: candidate count; out: fg flag (0/1)
    int* assign_inout,  // in: min-m candidate; out: final target gt idx
    float* __restrict__ mval,
    float* __restrict__ pos_align,
    float* __restrict__ pos_ovl) {
    int i = blockIdx.x * blockDim.x + threadIdx.x;
    if (i >= N_TOT) return;
    int b = i / NA, a = i - b * NA;

    int f = fg_inout[i];
    if (f <= 0) {
        fg_inout[i] = 0;
        assign_inout[i] = 0;  // argmax of all-zero column = 0
        mval[i] = 0.f;
        return;
    }

    float ax, ay;
    anchor_xy(a, ax, ay);
    float4 p = ((const float4*)pd_bboxes)[i];

    int m;
    if (f == 1) {
        m = assign_inout[i];
    } else {
        // multi: one_hot(argmax_m overlaps[b,:,a]); ties -> first m
        float best = -1.f;
        int bestm = 0;
        for (int mm = 0; mm < NM; ++mm) {
            float4 gg = ((const float4*)gt_bboxes)[b * NM + mm];
            float dmin = fminf(fminf(ax - gg.x, ay - gg.y),
                               fminf(gg.z - ax, gg.w - ay));
            float ov = 0.f;
            if (dmin > 1e-9f && mask_gt[b * NM + mm] > 0.f) {
                float w1 = gg.z - gg.x, h1 = gg.w - gg.y + 1e-7f;
                ov = ciou_clip_pre(gg.x, gg.y, gg.z, gg.w, w1 * h1,
                                   atanf(w1 / h1), p.x, p.y, p.z, p.w);
            }
            if (ov > best) { best = ov; bestm = mm; }
        }
        m = bestm;
    }

    float4 gg = ((const float4*)gt_bboxes)[b * NM + m];
    float dmin = fminf(fminf(ax - gg.x, ay - gg.y), fminf(gg.z - ax, gg.w - ay));
    float mv = 0.f, ovv = 0.f;
    if (dmin > 1e-9f && mask_gt[b * NM + m] > 0.f) {
        float w1 = gg.z - gg.x, h1 = gg.w - gg.y + 1e-7f;
        ovv = ciou_clip_pre(gg.x, gg.y, gg.z, gg.w, w1 * h1, atanf(w1 / h1),
                            p.x, p.y, p.z, p.w);
        float s = pd_scores[(size_t)i * NC + gt_labels[b * NM + m]];
        float ov2 = ovv * ovv;
        mv = s * ov2 * ov2 * ov2;
    }

    fg_inout[i] = 1;
    assign_inout[i] = m;
    mval[i] = mv;
    // values >= 0 -> int compare == float compare; order-independent.
    atomicMax((int*)&pos_align[b * NM + m], __float_as_int(mv));
    atomicMax((int*)&pos_ovl[b * NM + m], __float_as_int(ovv));
}

// Kernel 3 (fused final + scores): block of 256 anchors. Phase 1 computes
// labels/bboxes/fg/idx + (lbl, norm) into LDS; phase 2 writes the 80-wide
// one-hot scores rows fully coalesced as float4.
__global__ __launch_bounds__(256) void k_fused(
    const int* __restrict__ gt_labels,
    const float* __restrict__ gt_bboxes,
    const int* __restrict__ fgm,
    const int* __restrict__ tgt,
    const float* __restrict__ mval,
    const float* __restrict__ pos_align,
    const float* __restrict__ pos_ovl,
    float* __restrict__ out) {
    __shared__ int   slbl[256];
    __shared__ float snrm[256];
    const int tid = threadIdx.x;
    const int i = blockIdx.x * 256 + tid;

    if (i < N_TOT) {
        int b = i / NA;
        int m = tgt[i];
        int f = fgm[i];
        int lbl = gt_labels[b * NM + m];
        lbl = lbl < 0 ? 0 : lbl;
        float4 box = ((const float4*)gt_bboxes)[b * NM + m];
        float nrm = 0.f;
        if (f) nrm = mval[i] * pos_ovl[b * NM + m] / (pos_align[b * NM + m] + 1e-9f);

        out[i] = (float)lbl;                          // target_labels
        ((float4*)(out + N_TOT))[i] = box;            // target_bboxes
        out[(size_t)85 * N_TOT + i] = f ? 1.f : 0.f;  // fg_mask
        out[(size_t)86 * N_TOT + i] = (float)m;       // target_gt_idx
        slbl[tid] = f ? lbl : -1;
        snrm[tid] = nrm;
    }
    __syncthreads();

    float4* out4 = (float4*)(out + (size_t)5 * N_TOT) + (size_t)blockIdx.x * 256 * (NC / 4);
    const int base_anchor = blockIdx.x * 256;
#pragma unroll
    for (int it = 0; it < NC / 4; ++it) {
        int j = it * 256 + tid;
        int il = j / (NC / 4);
        if (base_anchor + il >= N_TOT) break;
        int c0 = (j - il * (NC / 4)) * 4;
        int lbl = slbl[il];
        float4 v = make_float4(0.f, 0.f, 0.f, 0.f);
        if (lbl >= c0 && lbl < c0 + 4) {
            float n = snrm[il];
            if (lbl == c0) v.x = n;
            else if (lbl == c0 + 1) v.y = n;
            else if (lbl == c0 + 2) v.z = n;
            else v.w = n;
        }
        out4[j] = v;
    }
}

extern "C" void kernel_launch(void* const* d_in, const int* in_sizes, int n_in,
                              void* d_out, int out_size, void* d_ws, size_t ws_size,
                              hipStream_t stream) {
    const float* pd_scores = (const float*)d_in[0];
    const float* pd_bboxes = (const float*)d_in[1];
    const int*   gt_labels = (const int*)d_in[3];
    // d_in[2] = anc_points (recomputed in-register), d_in[4] = gt_scores: unused
    const float* gt_bboxes = (const float*)d_in[5];
    const float* mask_gt   = (const float*)d_in[6];
    float* out = (float*)d_out;

    char* ws = (char*)d_ws;
    int*   fg        = (int*)ws;                          // N_TOT i32
    int*   assignm   = (int*)(ws + 4 * (size_t)N_TOT);    // N_TOT i32
    float* mval      = (float*)(ws + 8 * (size_t)N_TOT);  // N_TOT f32
    float* pos_align = (float*)(ws + 12 * (size_t)N_TOT); // BS*NM f32
    float* pos_ovl   = pos_align + BS * NM;               // BS*NM f32

    int nb = (N_TOT + 255) / 256;
    k_init<<<nb, 256, 0, stream>>>(fg, assignm, pos_align);

    k_topk<<<BS * NM, 256, 0, stream>>>(pd_scores, pd_bboxes, gt_labels,
                                        gt_bboxes, mask_gt, fg, assignm);

    k_assign<<<nb, 256, 0, stream>>>(pd_scores, pd_bboxes, gt_labels,
                                     gt_bboxes, mask_gt, fg, assignm, mval,
                                     pos_align, pos_ovl);

    k_fused<<<nb, 256, 0, stream>>>(gt_labels, gt_bboxes, fg, assignm, mval,
                                    pos_align, pos_ovl, out);
}

// Round 12
// 75.517 us; speedup vs baseline: 5.0462x; 1.0365x over previous
//
#include <hip/hip_runtime.h>
#include <math.h>

#define BS 32
#define NM 64
#define NA 8400
#define NC 80
#define TOPKK 13
#define N_TOT (BS * NA)
#define TPL 8  // per-lane candidate bound: ceil(1156/256)+ceil(324/256)+1 = 8

// CIoU (box1 = gt, box2 = pred) with gt-side terms hoisted; clipped at 0.
// Bit-identical to the reference _ciou (eps=1e-7) + jnp.clip(x, 0).
__device__ __forceinline__ float ciou_clip_pre(
    float gx1, float gy1, float gx2, float gy2,
    float area1, float at1,
    float px1, float py1, float px2, float py2) {
    const float eps = 1e-7f;
    float w2 = px2 - px1, h2 = py2 - py1 + eps;
    float iw = fmaxf(fminf(gx2, px2) - fmaxf(gx1, px1), 0.f);
    float ih = fmaxf(fminf(gy2, py2) - fmaxf(gy1, py1), 0.f);
    float inter = iw * ih;
    float uni = area1 + w2 * h2 - inter + eps;
    float iou = inter / uni;
    float cw = fmaxf(gx2, px2) - fminf(gx1, px1);
    float ch = fmaxf(gy2, py2) - fminf(gy1, py1);
    float c2 = cw * cw + ch * ch + eps;
    float dx = px1 + px2 - gx1 - gx2;
    float dy = py1 + py2 - gy1 - gy2;
    float rho2 = (dx * dx + dy * dy) * 0.25f;
    float dat = atanf(w2 / h2) - at1;
    float v = 0.4052847345693511f * dat * dat;  // 4/pi^2
    float al = v / (v - iou + 1.0000001f);      // 1.0 + eps
    return fmaxf(iou - (rho2 / c2 + v * al), 0.f);
}

__device__ __forceinline__ unsigned long long umax64(unsigned long long a,
                                                     unsigned long long b) {
    return a > b ? a : b;
}

// anchor index -> (ax, ay) exactly: (i+0.5)*stride, bit-identical to reference.
__device__ __forceinline__ void anchor_xy(int a, float& ax, float& ay) {
    int loc, n; float s;
    if (a < 6400)      { loc = a;        n = 80; s = 8.f;  }
    else if (a < 8000) { loc = a - 6400; n = 40; s = 16.f; }
    else               { loc = a - 8000; n = 20; s = 32.f; }
    int row = loc / n, col = loc - row * n;
    ax = ((float)col + 0.5f) * s;
    ay = ((float)row + 0.5f) * s;
}

__global__ __launch_bounds__(256) void k_init(int* __restrict__ fg,
                                              int* __restrict__ assignm,
                                              float* __restrict__ pos) {
    int i = blockIdx.x * blockDim.x + threadIdx.x;
    if (i < N_TOT) {
        fg[i] = 0;
        assignm[i] = 0x7FFFFFFF;
    }
    if (i < 2 * BS * NM) pos[i] = 0.f;
}

// Kernel 1 (best measured, R6): one 256-thread block per (b, m). Tight rect
// candidates (~450), three wave-uniform per-level scan loops, one atanf per
// candidate (gt-side hoisted), shift-register capture (per-lane count <= 8,
// capture-complete), rank-prune tail:
//   S1 per-wave head-rank (readlane) -> <=13 survivors/wave
//   S2 wave 0 ranks <=52 heads -> <=13 global survivors w/ pool slots
//   S3 survivors submit positive keys to <=104-entry LDS pool
//   S4 pool-rank; rank<13 <=> exact jax.lax.top_k top-13 -> scatter
//   S5 exact zero-metric filler via 64-lane ballot (nf = 13 - npos)
__global__ __launch_bounds__(256) void k_topk(
    const float* __restrict__ pd_scores,
    const float* __restrict__ pd_bboxes,
    const int* __restrict__ gt_labels,
    const float* __restrict__ gt_bboxes,
    const float* __restrict__ mask_gt,
    int* __restrict__ fg,
    int* __restrict__ assignm) {
    // XCD-aware swizzle (bijective: 2048 % 8 == 0)
    const int bm = ((blockIdx.x & 7) << 8) | (blockIdx.x >> 3);
    if (mask_gt[bm] <= 0.f) return;  // row contributes nothing (count=13@idx0)

    const int tid = threadIdx.x;
    const int lane = tid & 63, wid = tid >> 6;
    const int b = bm / NM;
    const int m = bm - b * NM;
    const float4 g = ((const float4*)gt_bboxes)[bm];
    const int lbl = gt_labels[bm];
    const float4* pb = (const float4*)(pd_bboxes + (size_t)b * NA * 4);
    const float* ps = pd_scores + (size_t)b * NA * NC + lbl;

    // gt-side CIoU invariants (block-uniform)
    const float w1 = g.z - g.x, h1 = g.w - g.y + 1e-7f;
    const float area1 = w1 * h1;
    const float at1 = atanf(w1 / h1);

    __shared__ unsigned long long sheads[4 * TOPKK];
    __shared__ int sowner[4 * TOPKK];
    __shared__ int ssubmit[256];
    __shared__ unsigned long long spool[TOPKK * TPL];
    __shared__ int snpos;

    if (tid < 4 * TOPKK) sheads[tid] = 0ull;
    if (tid < TOPKK * TPL) spool[tid] = 0ull;
    ssubmit[tid] = -1;
    if (tid == 0) snpos = 0;
    __syncthreads();  // B0

    // tight per-level rects (1e-4 margin; exact dmin test is the real filter)
    int c0_0, r0_0, w_0, cnt_0, c0_1, r0_1, w_1r, cnt_1, c0_2, r0_2, w_2, cnt_2;
    float iw_0, iw_1, iw_2;
#define MKRECT(NN, INVS, C0, R0, W, CNT, IW)                                   \
    {                                                                          \
        int c0 = (int)floorf(g.x * INVS - 0.5001f); if (c0 < 0) c0 = 0;        \
        int c1 = (int)ceilf (g.z * INVS - 0.4999f); if (c1 > NN - 1) c1 = NN - 1; \
        int r0 = (int)floorf(g.y * INVS - 0.5001f); if (r0 < 0) r0 = 0;        \
        int r1 = (int)ceilf (g.w * INVS - 0.4999f); if (r1 > NN - 1) r1 = NN - 1; \
        int w = c1 - c0 + 1; if (w < 0) w = 0;                                 \
        int h = r1 - r0 + 1; if (h < 0) h = 0;                                 \
        C0 = c0; R0 = r0; W = w; CNT = w * h; IW = w > 0 ? 1.f / (float)w : 0.f; \
    }
    MKRECT(80, 0.125f,   c0_0, r0_0, w_0,  cnt_0, iw_0)
    MKRECT(40, 0.0625f,  c0_1, r0_1, w_1r, cnt_1, iw_1)
    MKRECT(20, 0.03125f, c0_2, r0_2, w_2,  cnt_2, iw_2)
#undef MKRECT

    // shift-register candidate capture (named slots: static indexing only)
    unsigned long long t0 = 0, t1 = 0, t2 = 0, t3 = 0,
                       t4 = 0, t5 = 0, t6 = 0, t7 = 0;

#define PROCESS(AX, AY, A)                                                     \
    {                                                                          \
        float dmin = fminf(fminf((AX) - g.x, (AY) - g.y),                      \
                           fminf(g.z - (AX), g.w - (AY)));                     \
        if (dmin > 1e-9f) { /* exact mask_in_gts (EPS = 1e-9) */               \
            float4 p = pb[A];                                                  \
            float ov = ciou_clip_pre(g.x, g.y, g.z, g.w, area1, at1,           \
                                     p.x, p.y, p.z, p.w);                      \
            float sc = ps[(size_t)(A) * NC];                                   \
            float ov2 = ov * ov;                                               \
            float metric = sc * ov2 * ov2 * ov2; /* score * overlap^6 */       \
            unsigned long long key =                                           \
                ((unsigned long long)__float_as_uint(metric) << 32) |          \
                (unsigned)(NA - 1 - (A));                                      \
            t7 = t6; t6 = t5; t5 = t4; t4 = t3;                                \
            t3 = t2; t2 = t1; t1 = t0; t0 = key;                               \
        }                                                                      \
    }

    for (int j = tid; j < cnt_0; j += 256) {  // level 0: stride 8, n=80
        int rr = (int)(((float)j + 0.5f) * iw_0);
        int cc = j - rr * w_0;
        int row = r0_0 + rr, col = c0_0 + cc;
        PROCESS(((float)col + 0.5f) * 8.f, ((float)row + 0.5f) * 8.f,
                row * 80 + col)
    }
    for (int j = tid; j < cnt_1; j += 256) {  // level 1: stride 16, n=40
        int rr = (int)(((float)j + 0.5f) * iw_1);
        int cc = j - rr * w_1r;
        int row = r0_1 + rr, col = c0_1 + cc;
        PROCESS(((float)col + 0.5f) * 16.f, ((float)row + 0.5f) * 16.f,
                6400 + row * 40 + col)
    }
    for (int j = tid; j < cnt_2; j += 256) {  // level 2: stride 32, n=20
        int rr = (int)(((float)j + 0.5f) * iw_2);
        int cc = j - rr * w_2;
        int row = r0_2 + rr, col = c0_2 + cc;
        PROCESS(((float)col + 0.5f) * 32.f, ((float)row + 0.5f) * 32.f,
                8000 + row * 20 + col)
    }
#undef PROCESS

    // S1: per-wave head rank (readlane loop — register-only)
    {
        unsigned long long h =
            umax64(umax64(umax64(t0, t1), umax64(t2, t3)),
                   umax64(umax64(t4, t5), umax64(t6, t7)));
        unsigned hhi = (unsigned)(h >> 32), hlo = (unsigned)h;
        int wrank = 0;
#pragma unroll 8
        for (int l = 0; l < 64; ++l) {
            unsigned ohi = (unsigned)__builtin_amdgcn_readlane((int)hhi, l);
            unsigned olo = (unsigned)__builtin_amdgcn_readlane((int)hlo, l);
            wrank += (ohi > hhi) || (ohi == hhi && olo > hlo);
        }
        if (hhi != 0 && wrank < TOPKK) {
            sheads[wid * TOPKK + wrank] = h;
            sowner[wid * TOPKK + wrank] = tid;
        }
    }
    __syncthreads();  // B1

    // S2: wave 0 ranks the <=52 survivor heads
    if (wid == 0) {
        unsigned long long h2 = (lane < 4 * TOPKK) ? sheads[lane] : 0ull;
        unsigned h2hi = (unsigned)(h2 >> 32), h2lo = (unsigned)h2;
        int grank = 0;
#pragma unroll 4
        for (int l = 0; l < 4 * TOPKK; ++l) {
            unsigned ohi = (unsigned)__builtin_amdgcn_readlane((int)h2hi, l);
            unsigned olo = (unsigned)__builtin_amdgcn_readlane((int)h2lo, l);
            grank += (ohi > h2hi) || (ohi == h2hi && olo > h2lo);
        }
        if (lane < 4 * TOPKK && h2hi != 0 && grank < TOPKK)
            ssubmit[sowner[lane]] = grank;
    }
    __syncthreads();  // B2

    // S3: global survivors submit their positive keys to the pool
    {
        int s = ssubmit[tid];
        if (s >= 0) {
            unsigned long long* dst = &spool[s * TPL];
            if (t0 >> 32) dst[0] = t0;
            if (t1 >> 32) dst[1] = t1;
            if (t2 >> 32) dst[2] = t2;
            if (t3 >> 32) dst[3] = t3;
            if (t4 >> 32) dst[4] = t4;
            if (t5 >> 32) dst[5] = t5;
            if (t6 >> 32) dst[6] = t6;
            if (t7 >> 32) dst[7] = t7;
        }
    }
    __syncthreads();  // B3

    // S4: pool rank (broadcast LDS reads) -> exact top-13 scatter
    if (tid < TOPKK * TPL) {
        unsigned long long key = spool[tid];
        if ((key >> 32) != 0ull) {
            int rank = 0;
            for (int j = 0; j < TOPKK * TPL; ++j) rank += spool[j] > key;
            if (rank < TOPKK) {
                int a = NA - 1 - (int)(key & 0xFFFFFFFFull);
                atomicAdd(&fg[b * NA + a], 1);
                atomicMin(&assignm[b * NA + a], m);
                atomicAdd(&snpos, 1);
            }
        }
    }
    __syncthreads();  // B4

    // S5: fillers — remaining 13-npos slots = smallest-index zero-metric
    // anchors (provably within indices 0..63). In-box fillers scatter.
    if (wid == 0) {
        int nf = TOPKK - snpos;
        if (nf > 0) {
            int f = lane;  // anchor f: level-0 row 0 -> ax=(f+0.5)*8, ay=4
            float ax = ((float)f + 0.5f) * 8.f, ay = 4.0f;
            float dmin = fminf(fminf(ax - g.x, ay - g.y),
                               fminf(g.z - ax, g.w - ay));
            bool inbox = dmin > 1e-9f;
            float metric = 0.f;
            if (inbox) {
                float4 p = pb[f];
                float ov = ciou_clip_pre(g.x, g.y, g.z, g.w, area1, at1,
                                         p.x, p.y, p.z, p.w);
                float ov2 = ov * ov;
                metric = ps[(size_t)f * NC] * ov2 * ov2 * ov2;
            }
            bool pos = inbox && (metric > 0.f);
            unsigned long long pmask = __ballot(pos);
            if (inbox && !pos) {
                int rank = __popcll(~pmask & ((1ull << f) - 1ull));
                if (rank < nf) {
                    atomicAdd(&fg[b * NA + f], 1);
                    atomicMin(&assignm[b * NA + f], m);
                }
            }
        }
    }
}

// Kernel 2: one thread per (b, a). Resolve multi-assignment via masked-overlap
// argmax (tie -> lowest m), recompute assigned metric/overlap, reduce
// pos_align/pos_ovl per (b, m). Pred-side atanf hoisted out of the gt loop.
__global__ __launch_bounds__(256) void k_assign(
    const float* __restrict__ pd_scores,
    const float* __restrict__ pd_bboxes,
    const int* __restrict__ gt_labels,
    const float* __restrict__ gt_bboxes,
    const float* __restrict__ mask_gt,
    int* fg_inout,      // in: candidate count; out: fg flag (0/1)
    int* assign_inout,  // in: min-m candidate; out: final target gt idx
    float* __restrict__ mval,
    float* __restrict__ pos_align,
    float* __restrict__ pos_ovl) {
    int i = blockIdx.x * blockDim.x + threadIdx.x;
    if (i >= N_TOT) return;
    int b = i / NA, a = i - b * NA;

    int f = fg_inout[i];
    if (f <= 0) {
        fg_inout[i] = 0;
        assign_inout[i] = 0;  // argmax of all-zero column = 0
        mval[i] = 0.f;
        return;
    }

    float ax, ay;
    anchor_xy(a, ax, ay);
    float4 p = ((const float4*)pd_bboxes)[i];

    int m;
    if (f == 1) {
        m = assign_inout[i];
    } else {
        // multi: one_hot(argmax_m overlaps[b,:,a]); ties -> first m
        float best = -1.f;
        int bestm = 0;
        for (int mm = 0; mm < NM; ++mm) {
            float4 gg = ((const float4*)gt_bboxes)[b * NM + mm];
            float dmin = fminf(fminf(ax - gg.x, ay - gg.y),
                               fminf(gg.z - ax, gg.w - ay));
            float ov = 0.f;
            if (dmin > 1e-9f && mask_gt[b * NM + mm] > 0.f) {
                float w1 = gg.z - gg.x, h1 = gg.w - gg.y + 1e-7f;
                ov = ciou_clip_pre(gg.x, gg.y, gg.z, gg.w, w1 * h1,
                                   atanf(w1 / h1), p.x, p.y, p.z, p.w);
            }
            if (ov > best) { best = ov; bestm = mm; }
        }
        m = bestm;
    }

    float4 gg = ((const float4*)gt_bboxes)[b * NM + m];
    float dmin = fminf(fminf(ax - gg.x, ay - gg.y), fminf(gg.z - ax, gg.w - ay));
    float mv = 0.f, ovv = 0.f;
    if (dmin > 1e-9f && mask_gt[b * NM + m] > 0.f) {
        float w1 = gg.z - gg.x, h1 = gg.w - gg.y + 1e-7f;
        ovv = ciou_clip_pre(gg.x, gg.y, gg.z, gg.w, w1 * h1, atanf(w1 / h1),
                            p.x, p.y, p.z, p.w);
        float s = pd_scores[(size_t)i * NC + gt_labels[b * NM + m]];
        float ov2 = ovv * ovv;
        mv = s * ov2 * ov2 * ov2;
    }

    fg_inout[i] = 1;
    assign_inout[i] = m;
    mval[i] = mv;
    // values >= 0 -> int compare == float compare; order-independent.
    atomicMax((int*)&pos_align[b * NM + m], __float_as_int(mv));
    atomicMax((int*)&pos_ovl[b * NM + m], __float_as_int(ovv));
}

// Kernel 3 (fused final + scores): block of 256 anchors. Phase 1 computes
// labels/bboxes/fg/idx + (lbl, norm) into LDS; phase 2 writes the 80-wide
// one-hot scores rows fully coalesced as float4.
__global__ __launch_bounds__(256) void k_fused(
    const int* __restrict__ gt_labels,
    const float* __restrict__ gt_bboxes,
    const int* __restrict__ fgm,
    const int* __restrict__ tgt,
    const float* __restrict__ mval,
    const float* __restrict__ pos_align,
    const float* __restrict__ pos_ovl,
    float* __restrict__ out) {
    __shared__ int   slbl[256];
    __shared__ float snrm[256];
    const int tid = threadIdx.x;
    const int i = blockIdx.x * 256 + tid;

    if (i < N_TOT) {
        int b = i / NA;
        int m = tgt[i];
        int f = fgm[i];
        int lbl = gt_labels[b * NM + m];
        lbl = lbl < 0 ? 0 : lbl;
        float4 box = ((const float4*)gt_bboxes)[b * NM + m];
        float nrm = 0.f;
        if (f) nrm = mval[i] * pos_ovl[b * NM + m] / (pos_align[b * NM + m] + 1e-9f);

        out[i] = (float)lbl;                          // target_labels
        ((float4*)(out + N_TOT))[i] = box;            // target_bboxes
        out[(size_t)85 * N_TOT + i] = f ? 1.f : 0.f;  // fg_mask
        out[(size_t)86 * N_TOT + i] = (float)m;       // target_gt_idx
        slbl[tid] = f ? lbl : -1;
        snrm[tid] = nrm;
    }
    __syncthreads();

    float4* out4 = (float4*)(out + (size_t)5 * N_TOT) + (size_t)blockIdx.x * 256 * (NC / 4);
    const int base_anchor = blockIdx.x * 256;
#pragma unroll
    for (int it = 0; it < NC / 4; ++it) {
        int j = it * 256 + tid;
        int il = j / (NC / 4);
        if (base_anchor + il >= N_TOT) break;
        int c0 = (j - il * (NC / 4)) * 4;
        int lbl = slbl[il];
        float4 v = make_float4(0.f, 0.f, 0.f, 0.f);
        if (lbl >= c0 && lbl < c0 + 4) {
            float n = snrm[il];
            if (lbl == c0) v.x = n;
            else if (lbl == c0 + 1) v.y = n;
            else if (lbl == c0 + 2) v.z = n;
            else v.w = n;
        }
        out4[j] = v;
    }
}

extern "C" void kernel_launch(void* const* d_in, const int* in_sizes, int n_in,
                              void* d_out, int out_size, void* d_ws, size_t ws_size,
                              hipStream_t stream) {
    const float* pd_scores = (const float*)d_in[0];
    const float* pd_bboxes = (const float*)d_in[1];
    const int*   gt_labels = (const int*)d_in[3];
    // d_in[2] = anc_points (recomputed in-register), d_in[4] = gt_scores: unused
    const float* gt_bboxes = (const float*)d_in[5];
    const float* mask_gt   = (const float*)d_in[6];
    float* out = (float*)d_out;

    char* ws = (char*)d_ws;
    int*   fg        = (int*)ws;                          // N_TOT i32
    int*   assignm   = (int*)(ws + 4 * (size_t)N_TOT);    // N_TOT i32
    float* mval      = (float*)(ws + 8 * (size_t)N_TOT);  // N_TOT f32
    float* pos_align = (float*)(ws + 12 * (size_t)N_TOT); // BS*NM f32
    float* pos_ovl   = pos_align + BS * NM;               // BS*NM f32

    int nb = (N_TOT + 255) / 256;
    k_init<<<nb, 256, 0, stream>>>(fg, assignm, pos_align);

    k_topk<<<BS * NM, 256, 0, stream>>>(pd_scores, pd_bboxes, gt_labels,
                                        gt_bboxes, mask_gt, fg, assignm);

    k_assign<<<nb, 256, 0, stream>>>(pd_scores, pd_bboxes, gt_labels,
                                     gt_bboxes, mask_gt, fg, assignm, mval,
                                     pos_align, pos_ovl);

    k_fused<<<nb, 256, 0, stream>>>(gt_labels, gt_bboxes, fg, assignm, mval,
                                    pos_align, pos_ovl, out);
}